// Round 11
// baseline (1497.712 us; speedup 1.0000x reference)
//
#include <hip/hip_runtime.h>

// out[n,k] = softmax_k( 2*x_n.c_k - ||c_k||^2 )   (x_sqr cancels in softmax)
// 3-product bf16 split GEMM (logical K = 3*512 = 1536).
// Round 11 = Round 10 with the nontemporal builtin types fixed (ext_vector
// instead of HIP_vector_type). 128x256 tile, 8 waves of 64x64, 3 LDS buffers
// (72 KiB -> 2 blocks/CU), stage tile tt+2 during tt, ONE counted
// vmcnt(3)+lgkm(0)+barrier per tile. Conflict-free XOR swizzle. Non-temporal
// p16/norm traffic to keep the 16MB codebook L3-resident.

typedef __attribute__((ext_vector_type(8))) __bf16 bf16x8;
typedef __attribute__((ext_vector_type(4))) float f32x4;
typedef __attribute__((ext_vector_type(4))) unsigned int u32x4;

typedef __attribute__((address_space(1))) const void global_cvoid;
typedef __attribute__((address_space(3))) void lds_void;

__device__ inline unsigned short f32_to_bf16_rne(float f) {
    unsigned int u = __float_as_uint(f);
    unsigned int r = u + 0x7FFFu + ((u >> 16) & 1u);
    return (unsigned short)(r >> 16);
}
__device__ inline float bf16u_to_f32(unsigned short h) {
    return __uint_as_float(((unsigned int)h) << 16);
}

// ---------------- prep: fp32 -> bf16 hi/lo split ----------------
__global__ void split_kernel(const float* __restrict__ in,
                             unsigned short* __restrict__ hi,
                             unsigned short* __restrict__ lo, int n4) {
    int i = blockIdx.x * blockDim.x + threadIdx.x;
    int stride = gridDim.x * blockDim.x;
    for (; i < n4; i += stride) {
        float4 v = reinterpret_cast<const float4*>(in)[i];
        float vv[4] = {v.x, v.y, v.z, v.w};
        ushort4 hv, lv;
        unsigned short h[4], l[4];
#pragma unroll
        for (int j = 0; j < 4; ++j) {
            h[j] = f32_to_bf16_rne(vv[j]);
            float r = vv[j] - bf16u_to_f32(h[j]);
            l[j] = f32_to_bf16_rne(r);
        }
        hv.x = h[0]; hv.y = h[1]; hv.z = h[2]; hv.w = h[3];
        lv.x = l[0]; lv.y = l[1]; lv.z = l[2]; lv.w = l[3];
        reinterpret_cast<ushort4*>(hi)[i] = hv;
        reinterpret_cast<ushort4*>(lo)[i] = lv;
    }
}

// ---------------- prep: codebook row squared norms ----------------
__global__ void rowsq_kernel(const float* __restrict__ cb, float* __restrict__ out) {
    int row = blockIdx.x * 4 + (threadIdx.x >> 6);
    int lane = threadIdx.x & 63;
    const float4* p = reinterpret_cast<const float4*>(cb + (size_t)row * 512);
    float4 a = p[lane];
    float4 b = p[lane + 64];
    float s = a.x * a.x + a.y * a.y + a.z * a.z + a.w * a.w +
              b.x * b.x + b.y * b.y + b.z * b.z + b.w * b.w;
#pragma unroll
    for (int o = 32; o >= 1; o >>= 1) s += __shfl_xor(s, o);
    if (lane == 0) out[row] = s;
}

// ---------------- GEMM 128x256 ----------------
// Grid 8192 (256 bm x 32 bn, bijective XCD swizzle), 512 threads = 8 waves
// (2 wm x 4 wn), each wave owns 64x64. LDS: A[3][128x32] + B[3][256x32]
// bf16 = 72 KiB -> 2 blocks/CU. 48 tiles of BK=32 (3 products x 16 chunks).
// Swizzle: 16B-slot col c_phys = c_log ^ ((row>>1)&3) (0-conflict, r7-verified).

#define RD_A(bq_)                                                                 \
    { _Pragma("unroll") for (int m = 0; m < 4; ++m)                               \
        afr[m] = *(const bf16x8*)&ldsA[bq_][(a_slot + m * 64) * 8]; }

#define RD_B(bq_)                                                                 \
    { _Pragma("unroll") for (int n = 0; n < 4; ++n)                               \
        bfr[n] = *(const bf16x8*)&ldsB[bq_][(b_slot + n * 64) * 8]; }

#define ST(tt_, bq_)                                                              \
    { int prod_ = (tt_) >> 4, ko_ = ((tt_) & 15) * 32;                            \
      const unsigned short* Asrc_ = (prod_ < 2 ? Ah : Al) + arow0 + ko_;          \
      const unsigned short* Bsrc_ = (prod_ == 1 ? Bl : Bh) + brow0 + ko_;         \
      __builtin_amdgcn_global_load_lds((global_cvoid*)(Asrc_ + goffA),            \
          (lds_void*)&ldsA[bq_][slA], 16, 0, 0);                                  \
      _Pragma("unroll") for (int j = 0; j < 2; ++j)                               \
          __builtin_amdgcn_global_load_lds((global_cvoid*)(Bsrc_ + goffB[j]),     \
              (lds_void*)&ldsB[bq_][slB[j]], 16, 0, 0);                           \
    }

#define MM_ALL()                                                                  \
    { _Pragma("unroll") for (int m = 0; m < 4; ++m)                               \
      _Pragma("unroll") for (int n = 0; n < 4; ++n)                               \
          acc[m][n] = __builtin_amdgcn_mfma_f32_16x16x32_bf16(                    \
              afr[m], bfr[n], acc[m][n], 0, 0, 0); }

template <int F16>
__global__ __launch_bounds__(512, 4) void gemm_kernel(
    const unsigned short* __restrict__ Ah, const unsigned short* __restrict__ Al,
    const unsigned short* __restrict__ Bh, const unsigned short* __restrict__ Bl,
    const float* __restrict__ cbq, float* __restrict__ outf,
    unsigned short* __restrict__ p16, float* __restrict__ max_part,
    float* __restrict__ sum_part) {
    __shared__ __align__(16) unsigned short ldsA[3][4096];  // 24 KiB
    __shared__ __align__(16) unsigned short ldsB[3][8192];  // 48 KiB

    const int t = threadIdx.x;
    const int lane = t & 63;
    const int w = t >> 6;
    const int wm = w >> 2, wn = w & 3;  // 2 x 4 waves, each owns 64x64 output
    const int fr = lane & 15, fg = lane >> 4;

    int bid = blockIdx.x;
    int swz = (bid & 7) * 1024 + (bid >> 3);  // 8192 % 8 == 0 -> bijective
    const int bm = swz >> 5, bn = swz & 31;
    const int row0 = bm * 128, col0 = bn * 256;
    const size_t arow0 = (size_t)row0 * 512;
    const size_t brow0 = (size_t)col0 * 512;

    const int xsl = fg ^ ((fr >> 1) & 3);
    const int a_slot = (wm * 64 + fr) * 4 + xsl;  // + m*64
    const int b_slot = (wn * 64 + fr) * 4 + xsl;  // + n*64

    int goffA, slA, goffB[2], slB[2];
    {
        int s = t, r_ = s >> 2, cp_ = s & 3;
        goffA = r_ * 512 + (cp_ ^ ((r_ >> 1) & 3)) * 8;
        slA = s * 8;
    }
#pragma unroll
    for (int j = 0; j < 2; ++j) {
        int s = j * 512 + t, r_ = s >> 2, cp_ = s & 3;
        goffB[j] = r_ * 512 + (cp_ ^ ((r_ >> 1) & 3)) * 8;
        slB[j] = s * 8;
    }

    f32x4 acc[4][4] = {};
    bf16x8 afr[4], bfr[4];

    // prologue: stage tiles 0,1 into bufs 0,1 (6 loads); gate tile 0 (3 left)
    ST(0, 0);
    ST(1, 1);
    asm volatile("s_waitcnt vmcnt(3)\n\ts_barrier" ::: "memory");

    int bq = 0, sq = 2;
    for (int tt = 0; tt < 48; ++tt) {
        RD_B(bq);
        RD_A(bq);
        if (tt < 46) ST(tt + 2, sq);
        MM_ALL();  // compiler inserts fine-grained lgkmcnt before MFMA uses
        // close: my reads retired (lgkm 0 ~free), tile tt+1 landed for ALL
        // waves after the barrier; tile tt+2's 3 loads stay in flight (T4).
        if (tt < 46) {
            asm volatile("s_waitcnt vmcnt(3) lgkmcnt(0)\n\ts_barrier" ::: "memory");
        } else if (tt == 46) {
            asm volatile("s_waitcnt vmcnt(0) lgkmcnt(0)\n\ts_barrier" ::: "memory");
        } else {
            asm volatile("s_waitcnt lgkmcnt(0)\n\ts_barrier" ::: "memory");
        }
        bq = (bq == 2) ? 0 : bq + 1;
        sq = (sq == 2) ? 0 : sq + 1;
    }

    // ---- epilogue ----
    float* redm = (float*)&ldsA[0][0];  // [4 wn][128 rows]
    float* reds = redm + 512;

    float cq[4];
#pragma unroll
    for (int n = 0; n < 4; ++n) cq[n] = cbq[col0 + wn * 64 + n * 16 + fr];
#pragma unroll
    for (int m = 0; m < 4; ++m)
#pragma unroll
        for (int n = 0; n < 4; ++n)
#pragma unroll
            for (int r = 0; r < 4; ++r)
                acc[m][n][r] = 2.0f * acc[m][n][r] - cq[n];

    float rmx[4][4];
#pragma unroll
    for (int m = 0; m < 4; ++m)
#pragma unroll
        for (int r = 0; r < 4; ++r) {
            float v = fmaxf(fmaxf(acc[m][0][r], acc[m][1][r]),
                            fmaxf(acc[m][2][r], acc[m][3][r]));
#pragma unroll
            for (int o = 1; o < 16; o <<= 1) v = fmaxf(v, __shfl_xor(v, o));
            rmx[m][r] = v;
        }
    __syncthreads();  // all waves out of the K-loop before LDS reuse
    if (fr == 0) {
#pragma unroll
        for (int m = 0; m < 4; ++m)
#pragma unroll
            for (int r = 0; r < 4; ++r)
                redm[wn * 128 + wm * 64 + m * 16 + fg * 4 + r] = rmx[m][r];
    }
    __syncthreads();
#pragma unroll
    for (int m = 0; m < 4; ++m)
#pragma unroll
        for (int r = 0; r < 4; ++r) {
            int row = wm * 64 + m * 16 + fg * 4 + r;
            rmx[m][r] = fmaxf(fmaxf(redm[row], redm[128 + row]),
                              fmaxf(redm[256 + row], redm[384 + row]));
        }
#pragma unroll
    for (int m = 0; m < 4; ++m)
#pragma unroll
        for (int r = 0; r < 4; ++r) {
            float s = 0.f;
#pragma unroll
            for (int n = 0; n < 4; ++n) s += __expf(acc[m][n][r] - rmx[m][r]);
#pragma unroll
            for (int o = 1; o < 16; o <<= 1) s += __shfl_xor(s, o);
            if (fr == 0) reds[wn * 128 + wm * 64 + m * 16 + fg * 4 + r] = s;
        }
    __syncthreads();
    if (wn == 0 && fr == 0) {
#pragma unroll
        for (int m = 0; m < 4; ++m)
#pragma unroll
            for (int r = 0; r < 4; ++r) {
                int row = wm * 64 + m * 16 + fg * 4 + r;
                size_t gr = (size_t)(row0 + row);
                max_part[gr * 32 + bn] = rmx[m][r];
                sum_part[gr * 32 + bn] =
                    reds[row] + reds[128 + row] + reds[256 + row] + reds[384 + row];
            }
    }
#pragma unroll
    for (int m = 0; m < 4; ++m)
#pragma unroll
        for (int n = 0; n < 4; ++n)
#pragma unroll
            for (int r = 0; r < 4; ++r) {
                size_t gr = (size_t)(row0 + wm * 64 + m * 16 + fg * 4 + r);
                size_t gi = gr * 8192 + col0 + wn * 64 + n * 16 + fr;
                if constexpr (F16) {
                    union { _Float16 h; unsigned short u; } cv;
                    cv.h = (_Float16)__expf(acc[m][n][r] - rmx[m][r]);
                    __builtin_nontemporal_store(cv.u, &p16[gi]);
                } else {
                    outf[gi] = acc[m][n][r];
                }
            }
}

// ---------------- combine partials over 32 col-blocks per row ----------------
__global__ void combine_kernel(const float* __restrict__ max_part,
                               const float* __restrict__ sum_part,
                               float* __restrict__ row_m, float* __restrict__ row_is,
                               float* __restrict__ scale, int do_scale) {
    int row = blockIdx.x * 8 + (threadIdx.x >> 5);
    int l = threadIdx.x & 31;
    size_t off = (size_t)row * 32 + l;
    float m = max_part[off];
    float s = sum_part[off];
    float gm = m;
#pragma unroll
    for (int o = 16; o >= 1; o >>= 1) gm = fmaxf(gm, __shfl_xor(gm, o, 32));
    float c = s * __expf(m - gm);
#pragma unroll
    for (int o = 16; o >= 1; o >>= 1) c += __shfl_xor(c, o, 32);
    float inv = 1.0f / c;
    if (do_scale) scale[off] = __expf(m - gm) * inv;
    if (l == 0) {
        row_m[row] = gm;
        row_is[row] = inv;
    }
}

// ---------------- normalize: f32-logit path ----------------
__global__ void norm_kernel(float* __restrict__ out, const float* __restrict__ row_m,
                            const float* __restrict__ row_is) {
    size_t i = (size_t)blockIdx.x * blockDim.x + threadIdx.x;
    size_t stride = (size_t)gridDim.x * blockDim.x;
    const size_t n4 = 268435456ull / 4;
    float4* p = reinterpret_cast<float4*>(out);
    for (; i < n4; i += stride) {
        int row = (int)(i >> 11);
        float m = row_m[row];
        float is = row_is[row];
        float4 v = p[i];
        v.x = __expf(v.x - m) * is;
        v.y = __expf(v.y - m) * is;
        v.z = __expf(v.z - m) * is;
        v.w = __expf(v.w - m) * is;
        p[i] = v;
    }
}

// ---------------- normalize: f16-exp path (non-temporal, ext_vector) ----------------
__global__ void norm_f16_kernel(const unsigned short* __restrict__ p16,
                                const float* __restrict__ scale,
                                float* __restrict__ out) {
    size_t i = (size_t)blockIdx.x * blockDim.x + threadIdx.x;  // 8-elem group id
    size_t stride = (size_t)gridDim.x * blockDim.x;
    const size_t ng = 268435456ull / 8;
    const u32x4* src = reinterpret_cast<const u32x4*>(p16);
    f32x4* dst = reinterpret_cast<f32x4*>(out);
    for (; i < ng; i += stride) {
        int row = (int)(i >> 10);        // 1024 groups per row
        int bn = (int)((i >> 5) & 31);   // 32 groups per 256-col block
        float s = scale[(size_t)row * 32 + bn];
        union { u32x4 u; _Float16 h[8]; } cv;
        cv.u = __builtin_nontemporal_load(&src[i]);
        f32x4 o1, o2;
        o1.x = (float)cv.h[0] * s; o1.y = (float)cv.h[1] * s;
        o1.z = (float)cv.h[2] * s; o1.w = (float)cv.h[3] * s;
        o2.x = (float)cv.h[4] * s; o2.y = (float)cv.h[5] * s;
        o2.z = (float)cv.h[6] * s; o2.w = (float)cv.h[7] * s;
        __builtin_nontemporal_store(o1, &dst[i * 2]);
        __builtin_nontemporal_store(o2, &dst[i * 2 + 1]);
    }
}

extern "C" void kernel_launch(void* const* d_in, const int* in_sizes, int n_in,
                              void* d_out, int out_size, void* d_ws, size_t ws_size,
                              hipStream_t stream) {
    const float* x = (const float*)d_in[0];   // [32768,512]
    const float* cb = (const float*)d_in[1];  // [8192,512]
    float* out = (float*)d_out;               // [32768,8192]
    char* ws = (char*)d_ws;

    unsigned short* Xh = (unsigned short*)(ws);                 // 33,554,432
    unsigned short* Xl = (unsigned short*)(ws + 33554432ull);   // 33,554,432
    unsigned short* Ch = (unsigned short*)(ws + 67108864ull);   // 8,388,608
    unsigned short* Cl = (unsigned short*)(ws + 75497472ull);   // 8,388,608
    float* cbq       = (float*)(ws + 83886080ull);              // 32,768
    float* max_part  = (float*)(ws + 83918848ull);              // 4,194,304
    float* sum_part  = (float*)(ws + 88113152ull);              // 4,194,304
    float* row_m     = (float*)(ws + 92307456ull);              // 131,072
    float* row_is    = (float*)(ws + 92438528ull);              // 131,072
    float* scale     = (float*)(ws + 92569600ull);              // 4,194,304
    unsigned short* p16 = (unsigned short*)(ws + 96763904ull);  // 536,870,912 -> 633,634,816

    const bool f16path = (ws_size >= 633634816ull);

    split_kernel<<<2048, 256, 0, stream>>>(x, Xh, Xl, 32768 * 512 / 4);
    split_kernel<<<1024, 256, 0, stream>>>(cb, Ch, Cl, 8192 * 512 / 4);
    rowsq_kernel<<<2048, 256, 0, stream>>>(cb, cbq);
    if (f16path) {
        gemm_kernel<1><<<8192, 512, 0, stream>>>(Xh, Xl, Ch, Cl, cbq, out, p16,
                                                 max_part, sum_part);
        combine_kernel<<<4096, 256, 0, stream>>>(max_part, sum_part, row_m, row_is,
                                                 scale, 1);
        norm_f16_kernel<<<4096, 256, 0, stream>>>(p16, scale, out);
    } else {
        gemm_kernel<0><<<8192, 512, 0, stream>>>(Xh, Xl, Ch, Cl, cbq, out, p16,
                                                 max_part, sum_part);
        combine_kernel<<<4096, 256, 0, stream>>>(max_part, sum_part, row_m, row_is,
                                                 scale, 0);
        norm_kernel<<<4096, 256, 0, stream>>>(out, row_m, row_is);
    }
}

// Round 12
// 1410.313 us; speedup vs baseline: 1.0620x; 1.0620x over previous
//
#include <hip/hip_runtime.h>

// out[n,k] = softmax_k( 2*x_n.c_k - ||c_k||^2 )   (x_sqr cancels in softmax)
// 3-product bf16 split GEMM (logical K = 3*512 = 1536).
// Round 12: m201 geometry -- 256x256 block tile, 8 waves (2x4) each owning
// 128x64 (acc[8][4] = 128 VGPR, 43.7 FLOP/LDS-byte vs 32 before), BK=32 x
// 3-buffer LDS ring (96 KiB, 1 block/CU), stage tile tt+2 during tt, ONE
// counted vmcnt(4)+lgkm(0)+barrier close per tile. Zero-conflict XOR swizzle
// (r7-verified). Plain stores (r11: nt-store doubled WRITE_SIZE).

typedef __attribute__((ext_vector_type(8))) __bf16 bf16x8;
typedef __attribute__((ext_vector_type(4))) float f32x4;

typedef __attribute__((address_space(1))) const void global_cvoid;
typedef __attribute__((address_space(3))) void lds_void;

__device__ inline unsigned short f32_to_bf16_rne(float f) {
    unsigned int u = __float_as_uint(f);
    unsigned int r = u + 0x7FFFu + ((u >> 16) & 1u);
    return (unsigned short)(r >> 16);
}
__device__ inline float bf16u_to_f32(unsigned short h) {
    return __uint_as_float(((unsigned int)h) << 16);
}

// ---------------- prep: fp32 -> bf16 hi/lo split ----------------
__global__ void split_kernel(const float* __restrict__ in,
                             unsigned short* __restrict__ hi,
                             unsigned short* __restrict__ lo, int n4) {
    int i = blockIdx.x * blockDim.x + threadIdx.x;
    int stride = gridDim.x * blockDim.x;
    for (; i < n4; i += stride) {
        float4 v = reinterpret_cast<const float4*>(in)[i];
        float vv[4] = {v.x, v.y, v.z, v.w};
        ushort4 hv, lv;
        unsigned short h[4], l[4];
#pragma unroll
        for (int j = 0; j < 4; ++j) {
            h[j] = f32_to_bf16_rne(vv[j]);
            float r = vv[j] - bf16u_to_f32(h[j]);
            l[j] = f32_to_bf16_rne(r);
        }
        hv.x = h[0]; hv.y = h[1]; hv.z = h[2]; hv.w = h[3];
        lv.x = l[0]; lv.y = l[1]; lv.z = l[2]; lv.w = l[3];
        reinterpret_cast<ushort4*>(hi)[i] = hv;
        reinterpret_cast<ushort4*>(lo)[i] = lv;
    }
}

// ---------------- prep: codebook row squared norms ----------------
__global__ void rowsq_kernel(const float* __restrict__ cb, float* __restrict__ out) {
    int row = blockIdx.x * 4 + (threadIdx.x >> 6);
    int lane = threadIdx.x & 63;
    const float4* p = reinterpret_cast<const float4*>(cb + (size_t)row * 512);
    float4 a = p[lane];
    float4 b = p[lane + 64];
    float s = a.x * a.x + a.y * a.y + a.z * a.z + a.w * a.w +
              b.x * b.x + b.y * b.y + b.z * b.z + b.w * b.w;
#pragma unroll
    for (int o = 32; o >= 1; o >>= 1) s += __shfl_xor(s, o);
    if (lane == 0) out[row] = s;
}

// ---------------- GEMM 256x256, 8 waves of 128x64 ----------------
// Grid 4096 (128 bm x 32 bn, bijective XCD swizzle), 512 threads = 8 waves
// (2 wm x 4 wn). LDS: A[3][256x32] + B[3][256x32] bf16 = 96 KiB -> 1 block/CU.
// 48 tiles of BK=32 (3 products x 16 chunks).
// Swizzle: 16B-slot col c_phys = c_log ^ ((row>>1)&3) (0-conflict, r7-verified).

#define RD_A(bq_)                                                                 \
    { _Pragma("unroll") for (int m = 0; m < 8; ++m)                               \
        afr[m] = *(const bf16x8*)&ldsA[bq_][(a_slot + m * 64) * 8]; }

#define RD_B(bq_)                                                                 \
    { _Pragma("unroll") for (int n = 0; n < 4; ++n)                               \
        bfr[n] = *(const bf16x8*)&ldsB[bq_][(b_slot + n * 64) * 8]; }

#define ST(tt_, bq_)                                                              \
    { int prod_ = (tt_) >> 4, ko_ = ((tt_) & 15) * 32;                            \
      const unsigned short* Asrc_ = (prod_ < 2 ? Ah : Al) + arow0 + ko_;          \
      const unsigned short* Bsrc_ = (prod_ == 1 ? Bl : Bh) + brow0 + ko_;         \
      _Pragma("unroll") for (int j = 0; j < 2; ++j) {                             \
          __builtin_amdgcn_global_load_lds((global_cvoid*)(Asrc_ + goff[j]),      \
              (lds_void*)&ldsA[bq_][sl8[j]], 16, 0, 0);                           \
          __builtin_amdgcn_global_load_lds((global_cvoid*)(Bsrc_ + goff[j]),      \
              (lds_void*)&ldsB[bq_][sl8[j]], 16, 0, 0);                           \
      } }

#define MM_ALL()                                                                  \
    { _Pragma("unroll") for (int m = 0; m < 8; ++m)                               \
      _Pragma("unroll") for (int n = 0; n < 4; ++n)                               \
          acc[m][n] = __builtin_amdgcn_mfma_f32_16x16x32_bf16(                    \
              afr[m], bfr[n], acc[m][n], 0, 0, 0); }

template <int F16>
__global__ __launch_bounds__(512, 2) void gemm_kernel(
    const unsigned short* __restrict__ Ah, const unsigned short* __restrict__ Al,
    const unsigned short* __restrict__ Bh, const unsigned short* __restrict__ Bl,
    const float* __restrict__ cbq, float* __restrict__ outf,
    unsigned short* __restrict__ p16, float* __restrict__ max_part,
    float* __restrict__ sum_part) {
    __shared__ __align__(16) unsigned short ldsA[3][8192];  // 48 KiB
    __shared__ __align__(16) unsigned short ldsB[3][8192];  // 48 KiB

    const int t = threadIdx.x;
    const int lane = t & 63;
    const int w = t >> 6;
    const int wm = w >> 2, wn = w & 3;  // 2 x 4 waves, each owns 128x64 output
    const int fr = lane & 15, fg = lane >> 4;

    int bid = blockIdx.x;
    int swz = (bid & 7) * 512 + (bid >> 3);  // 4096 % 8 == 0 -> bijective
    const int bm = swz >> 5, bn = swz & 31;
    const int row0 = bm * 256, col0 = bn * 256;
    const size_t arow0 = (size_t)row0 * 512;
    const size_t brow0 = (size_t)col0 * 512;

    const int xsl = fg ^ ((fr >> 1) & 3);
    const int a_slot = (wm * 128 + fr) * 4 + xsl;  // + m*64, m in [0,8)
    const int b_slot = (wn * 64 + fr) * 4 + xsl;   // + n*64, n in [0,4)

    // staging: thread t, load j covers phys slot s = j*512 + t of a [256][32] unit
    int goff[2], sl8[2];
#pragma unroll
    for (int j = 0; j < 2; ++j) {
        int s = j * 512 + t, r_ = s >> 2, cp_ = s & 3;
        goff[j] = r_ * 512 + (cp_ ^ ((r_ >> 1) & 3)) * 8;
        sl8[j] = s * 8;
    }

    f32x4 acc[8][4] = {};
    bf16x8 afr[8], bfr[4];

    // prologue: stage tiles 0,1 into bufs 0,1 (8 loads); gate tile 0 (4 left)
    ST(0, 0);
    ST(1, 1);
    asm volatile("s_waitcnt vmcnt(4)\n\ts_barrier" ::: "memory");

    int bq = 0, sq = 2;
    for (int tt = 0; tt < 48; ++tt) {
        RD_B(bq);
        RD_A(bq);
        if (tt < 46) ST(tt + 2, sq);
        MM_ALL();  // compiler inserts fine-grained lgkmcnt before MFMA uses
        // close: my reads retired, tile tt+1 landed for ALL waves after the
        // barrier; tile tt+2's 4 loads stay in flight (T4 counted vmcnt).
        if (tt < 46) {
            asm volatile("s_waitcnt vmcnt(4) lgkmcnt(0)\n\ts_barrier" ::: "memory");
        } else if (tt == 46) {
            asm volatile("s_waitcnt vmcnt(0) lgkmcnt(0)\n\ts_barrier" ::: "memory");
        } else {
            asm volatile("s_waitcnt lgkmcnt(0)\n\ts_barrier" ::: "memory");
        }
        bq = (bq == 2) ? 0 : bq + 1;
        sq = (sq == 2) ? 0 : sq + 1;
    }

    // ---- epilogue ----
    float* redm = (float*)&ldsA[0][0];  // [4 wn][256 rows] = 4 KB
    float* reds = redm + 1024;          // [4 wn][256 rows] = 4 KB

    float cq[4];
#pragma unroll
    for (int n = 0; n < 4; ++n) cq[n] = cbq[col0 + wn * 64 + n * 16 + fr];
#pragma unroll
    for (int m = 0; m < 8; ++m)
#pragma unroll
        for (int n = 0; n < 4; ++n)
#pragma unroll
            for (int r = 0; r < 4; ++r)
                acc[m][n][r] = 2.0f * acc[m][n][r] - cq[n];

    float rmx[8][4];
#pragma unroll
    for (int m = 0; m < 8; ++m)
#pragma unroll
        for (int r = 0; r < 4; ++r) {
            float v = fmaxf(fmaxf(acc[m][0][r], acc[m][1][r]),
                            fmaxf(acc[m][2][r], acc[m][3][r]));
#pragma unroll
            for (int o = 1; o < 16; o <<= 1) v = fmaxf(v, __shfl_xor(v, o));
            rmx[m][r] = v;
        }
    __syncthreads();  // all waves out of the K-loop before LDS reuse
    if (fr == 0) {
#pragma unroll
        for (int m = 0; m < 8; ++m)
#pragma unroll
            for (int r = 0; r < 4; ++r)
                redm[wn * 256 + wm * 128 + m * 16 + fg * 4 + r] = rmx[m][r];
    }
    __syncthreads();
#pragma unroll
    for (int m = 0; m < 8; ++m)
#pragma unroll
        for (int r = 0; r < 4; ++r) {
            int row = wm * 128 + m * 16 + fg * 4 + r;
            rmx[m][r] = fmaxf(fmaxf(redm[row], redm[256 + row]),
                              fmaxf(redm[512 + row], redm[768 + row]));
        }
#pragma unroll
    for (int m = 0; m < 8; ++m)
#pragma unroll
        for (int r = 0; r < 4; ++r) {
            float s = 0.f;
#pragma unroll
            for (int n = 0; n < 4; ++n) s += __expf(acc[m][n][r] - rmx[m][r]);
#pragma unroll
            for (int o = 1; o < 16; o <<= 1) s += __shfl_xor(s, o);
            if (fr == 0) reds[wn * 256 + wm * 128 + m * 16 + fg * 4 + r] = s;
        }
    __syncthreads();
    if (wn == 0 && fr == 0) {
#pragma unroll
        for (int m = 0; m < 8; ++m)
#pragma unroll
            for (int r = 0; r < 4; ++r) {
                int row = wm * 128 + m * 16 + fg * 4 + r;
                size_t gr = (size_t)(row0 + row);
                max_part[gr * 32 + bn] = rmx[m][r];
                sum_part[gr * 32 + bn] =
                    reds[row] + reds[256 + row] + reds[512 + row] + reds[768 + row];
            }
    }
#pragma unroll
    for (int m = 0; m < 8; ++m)
#pragma unroll
        for (int n = 0; n < 4; ++n)
#pragma unroll
            for (int r = 0; r < 4; ++r) {
                size_t gr = (size_t)(row0 + wm * 128 + m * 16 + fg * 4 + r);
                size_t gi = gr * 8192 + col0 + wn * 64 + n * 16 + fr;
                if constexpr (F16) {
                    union { _Float16 h; unsigned short u; } cv;
                    cv.h = (_Float16)__expf(acc[m][n][r] - rmx[m][r]);
                    p16[gi] = cv.u;
                } else {
                    outf[gi] = acc[m][n][r];
                }
            }
}

// ---------------- combine partials over 32 col-blocks per row ----------------
__global__ void combine_kernel(const float* __restrict__ max_part,
                               const float* __restrict__ sum_part,
                               float* __restrict__ row_m, float* __restrict__ row_is,
                               float* __restrict__ scale, int do_scale) {
    int row = blockIdx.x * 8 + (threadIdx.x >> 5);
    int l = threadIdx.x & 31;
    size_t off = (size_t)row * 32 + l;
    float m = max_part[off];
    float s = sum_part[off];
    float gm = m;
#pragma unroll
    for (int o = 16; o >= 1; o >>= 1) gm = fmaxf(gm, __shfl_xor(gm, o, 32));
    float c = s * __expf(m - gm);
#pragma unroll
    for (int o = 16; o >= 1; o >>= 1) c += __shfl_xor(c, o, 32);
    float inv = 1.0f / c;
    if (do_scale) scale[off] = __expf(m - gm) * inv;
    if (l == 0) {
        row_m[row] = gm;
        row_is[row] = inv;
    }
}

// ---------------- normalize: f32-logit path ----------------
__global__ void norm_kernel(float* __restrict__ out, const float* __restrict__ row_m,
                            const float* __restrict__ row_is) {
    size_t i = (size_t)blockIdx.x * blockDim.x + threadIdx.x;
    size_t stride = (size_t)gridDim.x * blockDim.x;
    const size_t n4 = 268435456ull / 4;
    float4* p = reinterpret_cast<float4*>(out);
    for (; i < n4; i += stride) {
        int row = (int)(i >> 11);
        float m = row_m[row];
        float is = row_is[row];
        float4 v = p[i];
        v.x = __expf(v.x - m) * is;
        v.y = __expf(v.y - m) * is;
        v.z = __expf(v.z - m) * is;
        v.w = __expf(v.w - m) * is;
        p[i] = v;
    }
}

// ---------------- normalize: f16-exp path ----------------
__global__ void norm_f16_kernel(const unsigned short* __restrict__ p16,
                                const float* __restrict__ scale,
                                float* __restrict__ out) {
    size_t i = (size_t)blockIdx.x * blockDim.x + threadIdx.x;  // 8-elem group id
    size_t stride = (size_t)gridDim.x * blockDim.x;
    const size_t ng = 268435456ull / 8;
    const uint4* src = reinterpret_cast<const uint4*>(p16);
    float4* dst = reinterpret_cast<float4*>(out);
    for (; i < ng; i += stride) {
        int row = (int)(i >> 10);        // 1024 groups per row
        int bn = (int)((i >> 5) & 31);   // 32 groups per 256-col block
        float s = scale[(size_t)row * 32 + bn];
        union { uint4 u; _Float16 h[8]; } cv;
        cv.u = src[i];
        float4 o1, o2;
        o1.x = (float)cv.h[0] * s; o1.y = (float)cv.h[1] * s;
        o1.z = (float)cv.h[2] * s; o1.w = (float)cv.h[3] * s;
        o2.x = (float)cv.h[4] * s; o2.y = (float)cv.h[5] * s;
        o2.z = (float)cv.h[6] * s; o2.w = (float)cv.h[7] * s;
        dst[i * 2] = o1;
        dst[i * 2 + 1] = o2;
    }
}

extern "C" void kernel_launch(void* const* d_in, const int* in_sizes, int n_in,
                              void* d_out, int out_size, void* d_ws, size_t ws_size,
                              hipStream_t stream) {
    const float* x = (const float*)d_in[0];   // [32768,512]
    const float* cb = (const float*)d_in[1];  // [8192,512]
    float* out = (float*)d_out;               // [32768,8192]
    char* ws = (char*)d_ws;

    unsigned short* Xh = (unsigned short*)(ws);                 // 33,554,432
    unsigned short* Xl = (unsigned short*)(ws + 33554432ull);   // 33,554,432
    unsigned short* Ch = (unsigned short*)(ws + 67108864ull);   // 8,388,608
    unsigned short* Cl = (unsigned short*)(ws + 75497472ull);   // 8,388,608
    float* cbq       = (float*)(ws + 83886080ull);              // 32,768
    float* max_part  = (float*)(ws + 83918848ull);              // 4,194,304
    float* sum_part  = (float*)(ws + 88113152ull);              // 4,194,304
    float* row_m     = (float*)(ws + 92307456ull);              // 131,072
    float* row_is    = (float*)(ws + 92438528ull);              // 131,072
    float* scale     = (float*)(ws + 92569600ull);              // 4,194,304
    unsigned short* p16 = (unsigned short*)(ws + 96763904ull);  // 536,870,912 -> 633,634,816

    const bool f16path = (ws_size >= 633634816ull);

    split_kernel<<<2048, 256, 0, stream>>>(x, Xh, Xl, 32768 * 512 / 4);
    split_kernel<<<1024, 256, 0, stream>>>(cb, Ch, Cl, 8192 * 512 / 4);
    rowsq_kernel<<<2048, 256, 0, stream>>>(cb, cbq);
    if (f16path) {
        gemm_kernel<1><<<4096, 512, 0, stream>>>(Xh, Xl, Ch, Cl, cbq, out, p16,
                                                 max_part, sum_part);
        combine_kernel<<<4096, 256, 0, stream>>>(max_part, sum_part, row_m, row_is,
                                                 scale, 1);
        norm_f16_kernel<<<4096, 256, 0, stream>>>(p16, scale, out);
    } else {
        gemm_kernel<0><<<4096, 512, 0, stream>>>(Xh, Xl, Ch, Cl, cbq, out, p16,
                                                 max_part, sum_part);
        combine_kernel<<<4096, 256, 0, stream>>>(max_part, sum_part, row_m, row_is,
                                                 scale, 0);
        norm_kernel<<<4096, 256, 0, stream>>>(out, row_m, row_is);
    }
}